// Round 13
// baseline (118.039 us; speedup 1.0000x reference)
//
#include <hip/hip_runtime.h>
#include <hip/hip_bf16.h>
#include <math.h>

// ---------------- problem constants ----------------
#define N_ROWS 8192
#define DIM    512
#define NCLS   64
#define BM     128   // tile rows/cols
#define BK     64    // K step
#define NKT    (DIM / BK)                    // 8 K-tiles
#define NTILE  (N_ROWS / BM)                 // 64 tile-blocks per side
#define NTRI   (NTILE * (NTILE + 1) / 2)     // 2080 upper-tri tiles
#define NPBLK  520                           // persistent blocks = 8 * 65; 4 tiles each
#define TPB    4                             // tiles per block (520*4 = 2080)
#define NSLOT  NTILE                         // 64 partial slots
#define M_CONST 14.285714285714286f          // 1/T : the fixed max-shift (diagonal)
#define L2E     1.4426950408889634f          // log2(e)
#define M2_CONST 20.60992915555662f          // log2(e)/T (shift in exp2 units)
#define SCALE2  4.539815541256959f           // sqrt(log2(e)/T): MFMA outputs log2e*sim

using bf16x8 = __attribute__((ext_vector_type(8))) short;
using f32x4  = __attribute__((ext_vector_type(4))) float;

static __device__ inline unsigned short f2bf(float x) {
  unsigned u = __float_as_uint(x);
  unsigned r = u + 0x7FFFu + ((u >> 16) & 1u);   // RNE
  return (unsigned short)(r >> 16);
}

// ---- kernel 1: L2-normalize rows, scale by sqrt(log2e/T), cast bf16 -----------
__global__ __launch_bounds__(256) void normalize_rows(const float* __restrict__ proj,
                                                      unsigned short* __restrict__ outb) {
  const int row  = blockIdx.x * 4 + (threadIdx.x >> 6);
  const int lane = threadIdx.x & 63;
  const float4* src = (const float4*)(proj + (size_t)row * DIM);
  float4 a = src[lane * 2];
  float4 b = src[lane * 2 + 1];
  float ss = a.x*a.x + a.y*a.y + a.z*a.z + a.w*a.w
           + b.x*b.x + b.y*b.y + b.z*b.z + b.w*b.w;
#pragma unroll
  for (int off = 1; off < 64; off <<= 1) ss += __shfl_xor(ss, off);
  const float scale = SCALE2 / fmaxf(sqrtf(ss), 1e-12f);
  float v[8] = {a.x, a.y, a.z, a.w, b.x, b.y, b.z, b.w};
  unsigned short h[8];
#pragma unroll
  for (int i = 0; i < 8; ++i) h[i] = f2bf(v[i] * scale);
  uint4 packed;
  packed.x = (unsigned)h[0] | ((unsigned)h[1] << 16);
  packed.y = (unsigned)h[2] | ((unsigned)h[3] << 16);
  packed.z = (unsigned)h[4] | ((unsigned)h[5] << 16);
  packed.w = (unsigned)h[6] | ((unsigned)h[7] << 16);
  *(uint4*)(outb + (size_t)row * DIM + lane * 8) = packed;
}

// ---- kernel 2: class histogram, wave-privatized --------------------------------
__global__ __launch_bounds__(1024) void class_hist(const int* __restrict__ tgt,
                                                   int* __restrict__ hist) {
  __shared__ int h[16][NCLS];
  const int wid = threadIdx.x >> 6;
  const int lane = threadIdx.x & 63;
  if (lane < NCLS) h[wid][lane] = 0;
  __syncthreads();
  for (int i = threadIdx.x; i < N_ROWS; i += 1024) atomicAdd(&h[wid][tgt[i]], 1);
  __syncthreads();
  if (threadIdx.x < NCLS) {
    int s = 0;
#pragma unroll
    for (int w = 0; w < 16; ++w) s += h[w][threadIdx.x];
    hist[threadIdx.x] = s;
  }
}

// ---- kernel 3: PERSISTENT 128^2 tile GEMM (R9 tile body, 4 tiles/block) -------
// 520 blocks (2/CU), block b -> chunk (b&7)*65 + (b>>3) (XCD-bijective), tiles
// 4*chunk..4*chunk+3 (consecutive logicals: A-panel reused in L2 across the 4).
// Per tile, the R9-proven body: counted-vmcnt depth-1 pipeline, swizzled
// staging, fused exp2 epilogue. R12's bug fixed: targets write GUARDED to
// tid < 2*BM (512 threads, BM=128 -> threads 256+ must not touch tgc).
__global__ __launch_bounds__(512, 4) void supcon_tile(const unsigned short* __restrict__ p16,
                                                      const int* __restrict__ tgt,
                                                      float* __restrict__ dpart,
                                                      float* __restrict__ spart) {
  const int pbid  = (int)blockIdx.x;
  const int chunk = (pbid & 7) * (NPBLK / 8) + (pbid >> 3);   // 0..519, bijective

  __shared__ short As[2][BM * BK];   // 2 x 16 KB
  __shared__ short Bs[2][BM * BK];   // 2 x 16 KB
  __shared__ int   tgr[BM], tgc[BM];
  __shared__ float redE[4][BM], redS[4][BM];     // row partials per wn
  __shared__ float redEc[2][BM], redSc[2][BM];   // col partials per wm

  const int tid  = threadIdx.x;
  const int lane = tid & 63;
  const int wid  = tid >> 6;          // 0..7
  const int wm = wid >> 2, wn = wid & 3;          // 2 row-halves x 4 col-strips
  const int lhi = lane >> 4, llo = lane & 15;

#define STAGE(BUF, KT) do {                                                         \
  _Pragma("unroll")                                                                 \
  for (int j = 0; j < 2; ++j) {                                                     \
    const int g  = tid + j * 512;                                                   \
    const int r  = g >> 3, gp = g & 7;                                              \
    const int gl = gp ^ (r & 7);                                                    \
    const unsigned short* sA = p16 + (rowA0 + r) * DIM + (KT) * BK + gl * 8;        \
    const unsigned short* sB = p16 + (rowB0 + r) * DIM + (KT) * BK + gl * 8;        \
    __builtin_amdgcn_global_load_lds((const __attribute__((address_space(1))) void*)sA, \
        (__attribute__((address_space(3))) void*)&As[BUF][g * 8], 16, 0, 0);        \
    __builtin_amdgcn_global_load_lds((const __attribute__((address_space(1))) void*)sB, \
        (__attribute__((address_space(3))) void*)&Bs[BUF][g * 8], 16, 0, 0);        \
  }                                                                                 \
} while (0)

  for (int tt = 0; tt < TPB; ++tt) {
    const int logical = chunk * TPB + tt;     // 0..2079
    int rem = logical, br = 0;
    while (rem >= NTILE - br) { rem -= NTILE - br; ++br; }
    const int bc = br + rem;
    const size_t rowA0 = (size_t)br * BM;
    const size_t rowB0 = (size_t)bc * BM;

    if (tt > 0) __syncthreads();   // prev tile's redE/redS reads done before reuse

    STAGE(0, 0);
    if (tid < BM)            tgr[tid] = tgt[br * BM + tid];          // GUARDED
    else if (tid < 2 * BM)   tgc[tid - BM] = tgt[bc * BM + (tid - BM)];

    f32x4 zero = {0.f, 0.f, 0.f, 0.f};
    f32x4 acc[4][2];
#pragma unroll
    for (int i = 0; i < 4; ++i)
#pragma unroll
      for (int j = 0; j < 2; ++j) acc[i][j] = zero;

    __syncthreads();   // prologue drain; buf0 + targets ready

#pragma unroll
    for (int kt = 0; kt < NKT; ++kt) {
      const int cur = kt & 1, nxt = cur ^ 1;

      if (kt > 0) {
        __builtin_amdgcn_s_barrier();     // buf[nxt] reads (tile kt-1) done
        __builtin_amdgcn_sched_barrier(0);
      }
      if (kt + 1 < NKT) {
        STAGE(nxt, kt + 1);                              // 4 loads stay in flight
        asm volatile("s_waitcnt vmcnt(4)" ::: "memory"); // waits ONLY tile kt's
      } else {
        asm volatile("s_waitcnt vmcnt(0)" ::: "memory");
      }
      __builtin_amdgcn_sched_barrier(0);
      __builtin_amdgcn_s_barrier();                      // loads(kt) landed
      __builtin_amdgcn_sched_barrier(0);

#pragma unroll
      for (int ks = 0; ks < 2; ++ks) {
        bf16x8 af[4], bfr[2];
#pragma unroll
        for (int mi = 0; mi < 4; ++mi) {
          const int Ra = wm * 64 + mi * 16 + llo;
          af[mi] = *(const bf16x8*)&As[cur][Ra * BK + (((ks * 4 + lhi) ^ (Ra & 7)) * 8)];
        }
#pragma unroll
        for (int ni = 0; ni < 2; ++ni) {
          const int Rb = wn * 32 + ni * 16 + llo;
          bfr[ni] = *(const bf16x8*)&Bs[cur][Rb * BK + (((ks * 4 + lhi) ^ (Rb & 7)) * 8)];
        }
#pragma unroll
        for (int mi = 0; mi < 4; ++mi)
#pragma unroll
          for (int ni = 0; ni < 2; ++ni)
            acc[mi][ni] = __builtin_amdgcn_mfma_f32_16x16x32_bf16(af[mi], bfr[ni], acc[mi][ni], 0, 0, 0);
      }
    }

    // ---- epilogue (exp2 units): acc = log2e*sim; e = exp2(acc - M2) ----------
    const bool diag = (br == bc);
    const int tc0 = tgc[wn * 32 + llo];
    const int tc1 = tgc[wn * 32 + 16 + llo];
    float ecol[2] = {0.f, 0.f};
    float scol[2] = {0.f, 0.f};

#pragma unroll
    for (int mi = 0; mi < 4; ++mi) {
#pragma unroll
      for (int rg = 0; rg < 4; ++rg) {
        const int rin  = wm * 64 + mi * 16 + lhi * 4 + rg;   // row within tile
        const int trow = tgr[rin];
        float esum = 0.f, ssum = 0.f;
#pragma unroll
        for (int ni = 0; ni < 2; ++ni) {
          const int cin = wn * 32 + ni * 16 + llo;           // col within tile
          const float x = acc[mi][ni][rg];                   // log2e * sim
          const bool self = diag && (rin == cin);
          const float e = self ? 0.f : __builtin_amdgcn_exp2f(x - M2_CONST);
          const bool pos = (!self) && (trow == (ni ? tc1 : tc0));
          const float sv = pos ? x : 0.f;
          esum += e;  ssum += sv;
          ecol[ni] += e;  scol[ni] += sv;
        }
#pragma unroll
        for (int off = 1; off < 16; off <<= 1) {
          esum += __shfl_xor(esum, off);
          ssum += __shfl_xor(ssum, off);
        }
        if (llo == 0) { redE[wn][rin] = esum; redS[wn][rin] = ssum; }
      }
    }
    if (!diag) {  // transpose contribution: column sums -> rows of block bc
#pragma unroll
      for (int ni = 0; ni < 2; ++ni) {
        float ec = ecol[ni], sc = scol[ni];
        ec += __shfl_xor(ec, 16); ec += __shfl_xor(ec, 32);
        sc += __shfl_xor(sc, 16); sc += __shfl_xor(sc, 32);
        if (lhi == 0) {
          redEc[wm][wn * 32 + ni * 16 + llo] = ec;
          redSc[wm][wn * 32 + ni * 16 + llo] = sc;
        }
      }
    }
    __syncthreads();

    // cross-wave reduce; each [slot][row] cell written by exactly one tile:
    // row-path of (br,bc) under slot bc; col-path under slot br (br!=bc).
    if (tid < BM) {
      const float e = redE[0][tid] + redE[1][tid] + redE[2][tid] + redE[3][tid];
      const float s = redS[0][tid] + redS[1][tid] + redS[2][tid] + redS[3][tid];
      dpart[(size_t)bc * N_ROWS + rowA0 + tid] = e;
      spart[(size_t)bc * N_ROWS + rowA0 + tid] = s;
    } else if (tid < 2 * BM && !diag) {
      const int c = tid - BM;
      dpart[(size_t)br * N_ROWS + rowB0 + c] = redEc[0][c] + redEc[1][c];
      spart[(size_t)br * N_ROWS + rowB0 + c] = redSc[0][c] + redSc[1][c];
    }
  }
#undef STAGE
}

// ---- kernel 4: combine partials -> per-sample loss ----------------------------
__global__ __launch_bounds__(256) void combine_loss(const float* __restrict__ dpart,
                                                    const float* __restrict__ spart,
                                                    const int* __restrict__ tgt,
                                                    const int* __restrict__ hist,
                                                    float* __restrict__ out) {
  __shared__ float dsh[4][64], ssh[4][64];
  const int lane = threadIdx.x & 63;
  const int g    = threadIdx.x >> 6;
  const int r    = blockIdx.x * 64 + lane;
  float d = 0.f, s = 0.f;
  for (int k = g * (NSLOT / 4); k < (g + 1) * (NSLOT / 4); ++k) {
    d += dpart[(size_t)k * N_ROWS + r];
    s += spart[(size_t)k * N_ROWS + r];
  }
  dsh[g][lane] = d; ssh[g][lane] = s;
  __syncthreads();
  if (g == 0) {
    d = dsh[0][lane] + dsh[1][lane] + dsh[2][lane] + dsh[3][lane];
    s = ssh[0][lane] + ssh[1][lane] + ssh[2][lane] + ssh[3][lane];
    const int cnt = hist[tgt[r]] - 1;
    // s is in log2e*sim units -> divide back by L2E
    out[r] = (cnt > 0) ? (s / (L2E * (float)cnt) - M_CONST - logf(d + 1e-8f)) : 0.f;
  }
}

// ---------------- launcher ----------------
extern "C" void kernel_launch(void* const* d_in, const int* in_sizes, int n_in,
                              void* d_out, int out_size, void* d_ws, size_t ws_size,
                              hipStream_t stream) {
  const float* proj = (const float*)d_in[0];
  const int*   tgt  = (const int*)d_in[1];
  float* out = (float*)d_out;

  char* ws = (char*)d_ws;
  unsigned short* p16  = (unsigned short*)ws;                        // 8 MB
  float* dpart = (float*)(ws + (size_t)8  * 1024 * 1024);            // 2 MB (64 x 8192)
  float* spart = (float*)(ws + (size_t)10 * 1024 * 1024);            // 2 MB
  int*   hist  = (int*)(ws + (size_t)12 * 1024 * 1024);              // 256 B

  normalize_rows<<<N_ROWS / 4, 256, 0, stream>>>(proj, p16);
  class_hist<<<1, 1024, 0, stream>>>(tgt, hist);
  supcon_tile<<<NPBLK, 512, 0, stream>>>(p16, tgt, dpart, spart);
  combine_loss<<<N_ROWS / 64, 256, 0, stream>>>(dpart, spart, tgt, hist, out);
}

// Round 14
// 99.205 us; speedup vs baseline: 1.1898x; 1.1898x over previous
//
#include <hip/hip_runtime.h>
#include <hip/hip_bf16.h>
#include <math.h>

// ---------------- problem constants ----------------
#define N_ROWS 8192
#define DIM    512
#define NCLS   64
#define BM     256   // tile rows/cols (16 waves of 64x64)
#define BK     64    // K step
#define NKT    (DIM / BK)                    // 8 K-tiles
#define NTILE  (N_ROWS / BM)                 // 32 tile-blocks per side
#define NTRI   (NTILE * (NTILE + 1) / 2)     // 528 upper-tri tiles = 8 * 66
#define NSLOT  NTILE                         // 32 partial slots
#define M_CONST 14.285714285714286f          // 1/T : the fixed max-shift (diagonal)
#define L2E     1.4426950408889634f          // log2(e)
#define M2_CONST 20.60992915555662f          // log2(e)/T (shift in exp2 units)
#define SCALE2  4.539815541256959f           // sqrt(log2(e)/T): MFMA outputs log2e*sim

using bf16x8 = __attribute__((ext_vector_type(8))) short;
using f32x4  = __attribute__((ext_vector_type(4))) float;

static __device__ inline unsigned short f2bf(float x) {
  unsigned u = __float_as_uint(x);
  unsigned r = u + 0x7FFFu + ((u >> 16) & 1u);   // RNE
  return (unsigned short)(r >> 16);
}

// ---- kernel 1: L2-normalize rows, scale by sqrt(log2e/T), cast bf16 -----------
__global__ __launch_bounds__(256) void normalize_rows(const float* __restrict__ proj,
                                                      unsigned short* __restrict__ outb) {
  const int row  = blockIdx.x * 4 + (threadIdx.x >> 6);
  const int lane = threadIdx.x & 63;
  const float4* src = (const float4*)(proj + (size_t)row * DIM);
  float4 a = src[lane * 2];
  float4 b = src[lane * 2 + 1];
  float ss = a.x*a.x + a.y*a.y + a.z*a.z + a.w*a.w
           + b.x*b.x + b.y*b.y + b.z*b.z + b.w*b.w;
#pragma unroll
  for (int off = 1; off < 64; off <<= 1) ss += __shfl_xor(ss, off);
  const float scale = SCALE2 / fmaxf(sqrtf(ss), 1e-12f);
  float v[8] = {a.x, a.y, a.z, a.w, b.x, b.y, b.z, b.w};
  unsigned short h[8];
#pragma unroll
  for (int i = 0; i < 8; ++i) h[i] = f2bf(v[i] * scale);
  uint4 packed;
  packed.x = (unsigned)h[0] | ((unsigned)h[1] << 16);
  packed.y = (unsigned)h[2] | ((unsigned)h[3] << 16);
  packed.z = (unsigned)h[4] | ((unsigned)h[5] << 16);
  packed.w = (unsigned)h[6] | ((unsigned)h[7] << 16);
  *(uint4*)(outb + (size_t)row * DIM + lane * 8) = packed;
}

// ---- kernel 2: 256^2 tile, 16 waves of 64x64, counted-vmcnt pipeline ----------
// Per CU: 1 block, 16 waves (4/SIMD). Rounds per unit work 4x lower than the
// 128^2 family (2.06 tiles/CU x 8 K-tiles vs 8.125 x 8); LDS-read volume 33%
// lower (64x64 wave-tile: 16KB per 262k MAC). Per-wave regs = R2's measured
// 88 (acc[4][4]=64 f32 + frags) -> no spill under the 128 cap of (1024,4).
// Schedule: R9's proven body verbatim (s_barrier pair, STAGE 4 loads/thread,
// vmcnt(4) counted, never 0 mid-loop). Swizzle: key r&7, pre-swizzled global
// source, linear gload_lds dest, matching XOR on ds_read (0 conflicts).
__global__ __launch_bounds__(1024, 4) void supcon_tile(const unsigned short* __restrict__ p16,
                                                       const int* __restrict__ tgt,
                                                       float* __restrict__ dpart,
                                                       float* __restrict__ spart) {
  // XCD-chunked bijective remap (528 % 8 == 0), then triangle decode
  const int logical = ((int)blockIdx.x & 7) * (NTRI / 8) + ((int)blockIdx.x >> 3);
  int rem = logical, br = 0;
  while (rem >= NTILE - br) { rem -= NTILE - br; ++br; }
  const int bc = br + rem;

  __shared__ short As[2][BM * BK];   // 2 x 32 KB
  __shared__ short Bs[2][BM * BK];   // 2 x 32 KB
  __shared__ int   tgr[BM], tgc[BM];
  __shared__ float redE[4][BM], redS[4][BM];     // row partials per wn (4 col-strips)
  __shared__ float redEc[4][BM], redSc[4][BM];   // col partials per wm (4 row-bands)

  const int tid  = threadIdx.x;
  const int lane = tid & 63;
  const int wid  = tid >> 6;          // 0..15
  const int wm = wid >> 2, wn = wid & 3;          // 4x4 grid of 64x64 wave-tiles
  const int lhi = lane >> 4, llo = lane & 15;

  const size_t rowA0 = (size_t)br * BM;
  const size_t rowB0 = (size_t)bc * BM;

  // staging: 2048 granules (16B) per array; thread covers g = tid, tid+1024.
  // LDS dest linear in g; source granule pre-swizzled (key r&7). 4 loads/thread.
#define STAGE(BUF, KT) do {                                                         \
  _Pragma("unroll")                                                                 \
  for (int j = 0; j < 2; ++j) {                                                     \
    const int g  = tid + j * 1024;                                                  \
    const int r  = g >> 3, gp = g & 7;                                              \
    const int gl = gp ^ (r & 7);                                                    \
    const unsigned short* sA = p16 + (rowA0 + r) * DIM + (KT) * BK + gl * 8;        \
    const unsigned short* sB = p16 + (rowB0 + r) * DIM + (KT) * BK + gl * 8;        \
    __builtin_amdgcn_global_load_lds((const __attribute__((address_space(1))) void*)sA, \
        (__attribute__((address_space(3))) void*)&As[BUF][g * 8], 16, 0, 0);        \
    __builtin_amdgcn_global_load_lds((const __attribute__((address_space(1))) void*)sB, \
        (__attribute__((address_space(3))) void*)&Bs[BUF][g * 8], 16, 0, 0);        \
  }                                                                                 \
} while (0)

  STAGE(0, 0);
  if (tid < BM)            tgr[tid] = tgt[br * BM + tid];          // GUARDED
  else if (tid < 2 * BM)   tgc[tid - BM] = tgt[bc * BM + (tid - BM)];

  f32x4 zero = {0.f, 0.f, 0.f, 0.f};
  f32x4 acc[4][4];
#pragma unroll
  for (int i = 0; i < 4; ++i)
#pragma unroll
    for (int j = 0; j < 4; ++j) acc[i][j] = zero;

  __syncthreads();   // prologue drain; buf0 + targets ready

#pragma unroll
  for (int kt = 0; kt < NKT; ++kt) {
    const int cur = kt & 1, nxt = cur ^ 1;

    if (kt > 0) {
      __builtin_amdgcn_s_barrier();     // buf[nxt] reads (tile kt-1) done
      __builtin_amdgcn_sched_barrier(0);
    }
    if (kt + 1 < NKT) {
      STAGE(nxt, kt + 1);                              // 4 loads stay in flight
      asm volatile("s_waitcnt vmcnt(4)" ::: "memory"); // waits ONLY tile kt's
    } else {
      asm volatile("s_waitcnt vmcnt(0)" ::: "memory");
    }
    __builtin_amdgcn_sched_barrier(0);
    __builtin_amdgcn_s_barrier();                      // loads(kt) landed
    __builtin_amdgcn_sched_barrier(0);

#pragma unroll
    for (int ks = 0; ks < 2; ++ks) {
      bf16x8 af[4], bfr[4];
#pragma unroll
      for (int mi = 0; mi < 4; ++mi) {
        const int Ra = wm * 64 + mi * 16 + llo;
        af[mi] = *(const bf16x8*)&As[cur][Ra * BK + (((ks * 4 + lhi) ^ (Ra & 7)) * 8)];
      }
#pragma unroll
      for (int ni = 0; ni < 4; ++ni) {
        const int Rb = wn * 64 + ni * 16 + llo;
        bfr[ni] = *(const bf16x8*)&Bs[cur][Rb * BK + (((ks * 4 + lhi) ^ (Rb & 7)) * 8)];
      }
#pragma unroll
      for (int mi = 0; mi < 4; ++mi)
#pragma unroll
        for (int ni = 0; ni < 4; ++ni)
          acc[mi][ni] = __builtin_amdgcn_mfma_f32_16x16x32_bf16(af[mi], bfr[ni], acc[mi][ni], 0, 0, 0);
    }
  }
#undef STAGE

  // ---- epilogue (exp2 units): acc = log2e*sim; e = exp2(acc - M2) ------------
  const bool diag = (br == bc);
  int tc[4];
#pragma unroll
  for (int ni = 0; ni < 4; ++ni) tc[ni] = tgc[wn * 64 + ni * 16 + llo];
  float ecol[4] = {0.f, 0.f, 0.f, 0.f};
  float scol[4] = {0.f, 0.f, 0.f, 0.f};

#pragma unroll
  for (int mi = 0; mi < 4; ++mi) {
#pragma unroll
    for (int rg = 0; rg < 4; ++rg) {
      const int rin  = wm * 64 + mi * 16 + lhi * 4 + rg;   // row within tile
      const int trow = tgr[rin];
      float esum = 0.f, ssum = 0.f;
#pragma unroll
      for (int ni = 0; ni < 4; ++ni) {
        const int cin = wn * 64 + ni * 16 + llo;           // col within tile
        const float x = acc[mi][ni][rg];                   // log2e * sim
        const bool self = diag && (rin == cin);
        const float e = self ? 0.f : __builtin_amdgcn_exp2f(x - M2_CONST);
        const bool pos = (!self) && (trow == tc[ni]);
        const float sv = pos ? x : 0.f;
        esum += e;  ssum += sv;
        ecol[ni] += e;  scol[ni] += sv;
      }
#pragma unroll
      for (int off = 1; off < 16; off <<= 1) {
        esum += __shfl_xor(esum, off);
        ssum += __shfl_xor(ssum, off);
      }
      if (llo == 0) { redE[wn][rin] = esum; redS[wn][rin] = ssum; }
    }
  }
  if (!diag) {  // transpose contribution: column sums -> rows of block bc
#pragma unroll
    for (int ni = 0; ni < 4; ++ni) {
      float ec = ecol[ni], sc = scol[ni];
      ec += __shfl_xor(ec, 16); ec += __shfl_xor(ec, 32);
      sc += __shfl_xor(sc, 16); sc += __shfl_xor(sc, 32);
      if (lhi == 0) {
        redEc[wm][wn * 64 + ni * 16 + llo] = ec;
        redSc[wm][wn * 64 + ni * 16 + llo] = sc;
      }
    }
  }
  __syncthreads();

  // cross-wave reduce; each [slot][row] cell written by exactly one block:
  // row-path of (br,bc) under slot bc; col-path under slot br (br!=bc).
  if (tid < BM) {
    const float e = redE[0][tid] + redE[1][tid] + redE[2][tid] + redE[3][tid];
    const float s = redS[0][tid] + redS[1][tid] + redS[2][tid] + redS[3][tid];
    dpart[(size_t)bc * N_ROWS + rowA0 + tid] = e;
    spart[(size_t)bc * N_ROWS + rowA0 + tid] = s;
  } else if (tid < 2 * BM && !diag) {
    const int c = tid - BM;
    dpart[(size_t)br * N_ROWS + rowB0 + c] = redEc[0][c] + redEc[1][c] + redEc[2][c] + redEc[3][c];
    spart[(size_t)br * N_ROWS + rowB0 + c] = redSc[0][c] + redSc[1][c] + redSc[2][c] + redSc[3][c];
  }
}

// ---- kernel 3: combine partials -> per-sample loss (hist inlined) -------------
__global__ __launch_bounds__(256) void combine_loss(const float* __restrict__ dpart,
                                                    const float* __restrict__ spart,
                                                    const int* __restrict__ tgt,
                                                    float* __restrict__ out) {
  __shared__ float dsh[4][64], ssh[4][64];
  __shared__ int   hloc[NCLS];
  const int tid  = threadIdx.x;
  const int lane = tid & 63;
  const int g    = tid >> 6;
  const int r    = blockIdx.x * 64 + lane;

  if (tid < NCLS) hloc[tid] = 0;
  __syncthreads();
  for (int i = tid; i < N_ROWS; i += 256) atomicAdd(&hloc[tgt[i]], 1);

  float d = 0.f, s = 0.f;
  for (int k = g * (NSLOT / 4); k < (g + 1) * (NSLOT / 4); ++k) {
    d += dpart[(size_t)k * N_ROWS + r];
    s += spart[(size_t)k * N_ROWS + r];
  }
  dsh[g][lane] = d; ssh[g][lane] = s;
  __syncthreads();
  if (g == 0) {
    d = dsh[0][lane] + dsh[1][lane] + dsh[2][lane] + dsh[3][lane];
    s = ssh[0][lane] + ssh[1][lane] + ssh[2][lane] + ssh[3][lane];
    const int cnt = hloc[tgt[r]] - 1;
    // s is in log2e*sim units -> divide back by L2E
    out[r] = (cnt > 0) ? (s / (L2E * (float)cnt) - M_CONST - logf(d + 1e-8f)) : 0.f;
  }
}

// ---------------- launcher ----------------
extern "C" void kernel_launch(void* const* d_in, const int* in_sizes, int n_in,
                              void* d_out, int out_size, void* d_ws, size_t ws_size,
                              hipStream_t stream) {
  const float* proj = (const float*)d_in[0];
  const int*   tgt  = (const int*)d_in[1];
  float* out = (float*)d_out;

  char* ws = (char*)d_ws;
  unsigned short* p16  = (unsigned short*)ws;                        // 8 MB
  float* dpart = (float*)(ws + (size_t)8 * 1024 * 1024);             // 1 MB (32 x 8192)
  float* spart = (float*)(ws + (size_t)9 * 1024 * 1024);             // 1 MB

  normalize_rows<<<N_ROWS / 4, 256, 0, stream>>>(proj, p16);
  supcon_tile<<<NTRI, 1024, 0, stream>>>(p16, tgt, dpart, spart);
  combine_loss<<<N_ROWS / 64, 256, 0, stream>>>(dpart, spart, tgt, out);
}

// Round 15
// 98.833 us; speedup vs baseline: 1.1943x; 1.0038x over previous
//
#include <hip/hip_runtime.h>
#include <hip/hip_bf16.h>
#include <math.h>

// ---------------- problem constants ----------------
#define N_ROWS 8192
#define DIM    512
#define NCLS   64
#define BM     256   // tile rows/cols (16 waves of 64x64)
#define BK     64    // K step
#define NKT    (DIM / BK)                    // 8 K-tiles
#define NTILE  (N_ROWS / BM)                 // 32 tile-blocks per side
#define NTRI   (NTILE * (NTILE + 1) / 2)     // 528 upper-tri tiles = 8 * 66
#define NSLOT  NTILE                         // 32 partial slots
#define M_CONST 14.285714285714286f          // 1/T : the fixed max-shift (diagonal)
#define L2E     1.4426950408889634f          // log2(e)
#define M2_CONST 20.60992915555662f          // log2(e)/T (shift in exp2 units)
#define SCALE2  4.539815541256959f           // sqrt(log2(e)/T): MFMA outputs log2e*sim

using bf16x8 = __attribute__((ext_vector_type(8))) short;
using f32x4  = __attribute__((ext_vector_type(4))) float;

static __device__ inline unsigned short f2bf(float x) {
  unsigned u = __float_as_uint(x);
  unsigned r = u + 0x7FFFu + ((u >> 16) & 1u);   // RNE
  return (unsigned short)(r >> 16);
}

// ---- kernel 1: L2-normalize rows, scale by sqrt(log2e/T), cast bf16 -----------
__global__ __launch_bounds__(256) void normalize_rows(const float* __restrict__ proj,
                                                      unsigned short* __restrict__ outb) {
  const int row  = blockIdx.x * 4 + (threadIdx.x >> 6);
  const int lane = threadIdx.x & 63;
  const float4* src = (const float4*)(proj + (size_t)row * DIM);
  float4 a = src[lane * 2];
  float4 b = src[lane * 2 + 1];
  float ss = a.x*a.x + a.y*a.y + a.z*a.z + a.w*a.w
           + b.x*b.x + b.y*b.y + b.z*b.z + b.w*b.w;
#pragma unroll
  for (int off = 1; off < 64; off <<= 1) ss += __shfl_xor(ss, off);
  const float scale = SCALE2 / fmaxf(sqrtf(ss), 1e-12f);
  float v[8] = {a.x, a.y, a.z, a.w, b.x, b.y, b.z, b.w};
  unsigned short h[8];
#pragma unroll
  for (int i = 0; i < 8; ++i) h[i] = f2bf(v[i] * scale);
  uint4 packed;
  packed.x = (unsigned)h[0] | ((unsigned)h[1] << 16);
  packed.y = (unsigned)h[2] | ((unsigned)h[3] << 16);
  packed.z = (unsigned)h[4] | ((unsigned)h[5] << 16);
  packed.w = (unsigned)h[6] | ((unsigned)h[7] << 16);
  *(uint4*)(outb + (size_t)row * DIM + lane * 8) = packed;
}

// ---- kernel 2: 256^2 tile, 16 waves of 64x64, counted-vmcnt pipeline ----------
// Identical to R14 EXCEPT __launch_bounds__(1024) with NO min-waves arg:
// R14's (1024,4) made the compiler allocate for an 8-wave/SIMD target ->
// 64-VGPR cap -> ~50 regs/thread spilled (WRITE_SIZE 48.5MB). This kernel
// needs ~110 regs (acc 64 f32 + frags + addressing); at 149KB LDS only
// 1 block/CU fits (4 waves/SIMD) whose natural budget is 128 VGPR.
__global__ __launch_bounds__(1024) void supcon_tile(const unsigned short* __restrict__ p16,
                                                    const int* __restrict__ tgt,
                                                    float* __restrict__ dpart,
                                                    float* __restrict__ spart) {
  // XCD-chunked bijective remap (528 % 8 == 0), then triangle decode
  const int logical = ((int)blockIdx.x & 7) * (NTRI / 8) + ((int)blockIdx.x >> 3);
  int rem = logical, br = 0;
  while (rem >= NTILE - br) { rem -= NTILE - br; ++br; }
  const int bc = br + rem;

  __shared__ short As[2][BM * BK];   // 2 x 32 KB
  __shared__ short Bs[2][BM * BK];   // 2 x 32 KB
  __shared__ int   tgr[BM], tgc[BM];
  __shared__ float redE[4][BM], redS[4][BM];     // row partials per wn (4 col-strips)
  __shared__ float redEc[4][BM], redSc[4][BM];   // col partials per wm (4 row-bands)

  const int tid  = threadIdx.x;
  const int lane = tid & 63;
  const int wid  = tid >> 6;          // 0..15
  const int wm = wid >> 2, wn = wid & 3;          // 4x4 grid of 64x64 wave-tiles
  const int lhi = lane >> 4, llo = lane & 15;

  const size_t rowA0 = (size_t)br * BM;
  const size_t rowB0 = (size_t)bc * BM;

  // staging: 2048 granules (16B) per array; thread covers g = tid, tid+1024.
  // LDS dest linear in g; source granule pre-swizzled (key r&7). 4 loads/thread.
#define STAGE(BUF, KT) do {                                                         \
  _Pragma("unroll")                                                                 \
  for (int j = 0; j < 2; ++j) {                                                     \
    const int g  = tid + j * 1024;                                                  \
    const int r  = g >> 3, gp = g & 7;                                              \
    const int gl = gp ^ (r & 7);                                                    \
    const unsigned short* sA = p16 + (rowA0 + r) * DIM + (KT) * BK + gl * 8;        \
    const unsigned short* sB = p16 + (rowB0 + r) * DIM + (KT) * BK + gl * 8;        \
    __builtin_amdgcn_global_load_lds((const __attribute__((address_space(1))) void*)sA, \
        (__attribute__((address_space(3))) void*)&As[BUF][g * 8], 16, 0, 0);        \
    __builtin_amdgcn_global_load_lds((const __attribute__((address_space(1))) void*)sB, \
        (__attribute__((address_space(3))) void*)&Bs[BUF][g * 8], 16, 0, 0);        \
  }                                                                                 \
} while (0)

  STAGE(0, 0);
  if (tid < BM)            tgr[tid] = tgt[br * BM + tid];          // GUARDED
  else if (tid < 2 * BM)   tgc[tid - BM] = tgt[bc * BM + (tid - BM)];

  f32x4 zero = {0.f, 0.f, 0.f, 0.f};
  f32x4 acc[4][4];
#pragma unroll
  for (int i = 0; i < 4; ++i)
#pragma unroll
    for (int j = 0; j < 4; ++j) acc[i][j] = zero;

  __syncthreads();   // prologue drain; buf0 + targets ready

#pragma unroll
  for (int kt = 0; kt < NKT; ++kt) {
    const int cur = kt & 1, nxt = cur ^ 1;

    if (kt > 0) {
      __builtin_amdgcn_s_barrier();     // buf[nxt] reads (tile kt-1) done
      __builtin_amdgcn_sched_barrier(0);
    }
    if (kt + 1 < NKT) {
      STAGE(nxt, kt + 1);                              // 4 loads stay in flight
      asm volatile("s_waitcnt vmcnt(4)" ::: "memory"); // waits ONLY tile kt's
    } else {
      asm volatile("s_waitcnt vmcnt(0)" ::: "memory");
    }
    __builtin_amdgcn_sched_barrier(0);
    __builtin_amdgcn_s_barrier();                      // loads(kt) landed
    __builtin_amdgcn_sched_barrier(0);

#pragma unroll
    for (int ks = 0; ks < 2; ++ks) {
      bf16x8 af[4], bfr[4];
#pragma unroll
      for (int mi = 0; mi < 4; ++mi) {
        const int Ra = wm * 64 + mi * 16 + llo;
        af[mi] = *(const bf16x8*)&As[cur][Ra * BK + (((ks * 4 + lhi) ^ (Ra & 7)) * 8)];
      }
#pragma unroll
      for (int ni = 0; ni < 4; ++ni) {
        const int Rb = wn * 64 + ni * 16 + llo;
        bfr[ni] = *(const bf16x8*)&Bs[cur][Rb * BK + (((ks * 4 + lhi) ^ (Rb & 7)) * 8)];
      }
#pragma unroll
      for (int mi = 0; mi < 4; ++mi)
#pragma unroll
        for (int ni = 0; ni < 4; ++ni)
          acc[mi][ni] = __builtin_amdgcn_mfma_f32_16x16x32_bf16(af[mi], bfr[ni], acc[mi][ni], 0, 0, 0);
    }
  }
#undef STAGE

  // ---- epilogue (exp2 units): acc = log2e*sim; e = exp2(acc - M2) ------------
  const bool diag = (br == bc);
  int tc[4];
#pragma unroll
  for (int ni = 0; ni < 4; ++ni) tc[ni] = tgc[wn * 64 + ni * 16 + llo];
  float ecol[4] = {0.f, 0.f, 0.f, 0.f};
  float scol[4] = {0.f, 0.f, 0.f, 0.f};

#pragma unroll
  for (int mi = 0; mi < 4; ++mi) {
#pragma unroll
    for (int rg = 0; rg < 4; ++rg) {
      const int rin  = wm * 64 + mi * 16 + lhi * 4 + rg;   // row within tile
      const int trow = tgr[rin];
      float esum = 0.f, ssum = 0.f;
#pragma unroll
      for (int ni = 0; ni < 4; ++ni) {
        const int cin = wn * 64 + ni * 16 + llo;           // col within tile
        const float x = acc[mi][ni][rg];                   // log2e * sim
        const bool self = diag && (rin == cin);
        const float e = self ? 0.f : __builtin_amdgcn_exp2f(x - M2_CONST);
        const bool pos = (!self) && (trow == tc[ni]);
        const float sv = pos ? x : 0.f;
        esum += e;  ssum += sv;
        ecol[ni] += e;  scol[ni] += sv;
      }
#pragma unroll
      for (int off = 1; off < 16; off <<= 1) {
        esum += __shfl_xor(esum, off);
        ssum += __shfl_xor(ssum, off);
      }
      if (llo == 0) { redE[wn][rin] = esum; redS[wn][rin] = ssum; }
    }
  }
  if (!diag) {  // transpose contribution: column sums -> rows of block bc
#pragma unroll
    for (int ni = 0; ni < 4; ++ni) {
      float ec = ecol[ni], sc = scol[ni];
      ec += __shfl_xor(ec, 16); ec += __shfl_xor(ec, 32);
      sc += __shfl_xor(sc, 16); sc += __shfl_xor(sc, 32);
      if (lhi == 0) {
        redEc[wm][wn * 64 + ni * 16 + llo] = ec;
        redSc[wm][wn * 64 + ni * 16 + llo] = sc;
      }
    }
  }
  __syncthreads();

  // cross-wave reduce; each [slot][row] cell written by exactly one block:
  // row-path of (br,bc) under slot bc; col-path under slot br (br!=bc).
  if (tid < BM) {
    const float e = redE[0][tid] + redE[1][tid] + redE[2][tid] + redE[3][tid];
    const float s = redS[0][tid] + redS[1][tid] + redS[2][tid] + redS[3][tid];
    dpart[(size_t)bc * N_ROWS + rowA0 + tid] = e;
    spart[(size_t)bc * N_ROWS + rowA0 + tid] = s;
  } else if (tid < 2 * BM && !diag) {
    const int c = tid - BM;
    dpart[(size_t)br * N_ROWS + rowB0 + c] = redEc[0][c] + redEc[1][c] + redEc[2][c] + redEc[3][c];
    spart[(size_t)br * N_ROWS + rowB0 + c] = redSc[0][c] + redSc[1][c] + redSc[2][c] + redSc[3][c];
  }
}

// ---- kernel 3: combine partials -> per-sample loss (hist inlined) -------------
__global__ __launch_bounds__(256) void combine_loss(const float* __restrict__ dpart,
                                                    const float* __restrict__ spart,
                                                    const int* __restrict__ tgt,
                                                    float* __restrict__ out) {
  __shared__ float dsh[4][64], ssh[4][64];
  __shared__ int   hloc[NCLS];
  const int tid  = threadIdx.x;
  const int lane = tid & 63;
  const int g    = tid >> 6;
  const int r    = blockIdx.x * 64 + lane;

  if (tid < NCLS) hloc[tid] = 0;
  __syncthreads();
  for (int i = tid; i < N_ROWS; i += 256) atomicAdd(&hloc[tgt[i]], 1);

  float d = 0.f, s = 0.f;
  for (int k = g * (NSLOT / 4); k < (g + 1) * (NSLOT / 4); ++k) {
    d += dpart[(size_t)k * N_ROWS + r];
    s += spart[(size_t)k * N_ROWS + r];
  }
  dsh[g][lane] = d; ssh[g][lane] = s;
  __syncthreads();
  if (g == 0) {
    d = dsh[0][lane] + dsh[1][lane] + dsh[2][lane] + dsh[3][lane];
    s = ssh[0][lane] + ssh[1][lane] + ssh[2][lane] + ssh[3][lane];
    const int cnt = hloc[tgt[r]] - 1;
    // s is in log2e*sim units -> divide back by L2E
    out[r] = (cnt > 0) ? (s / (L2E * (float)cnt) - M_CONST - logf(d + 1e-8f)) : 0.f;
  }
}

// ---------------- launcher ----------------
extern "C" void kernel_launch(void* const* d_in, const int* in_sizes, int n_in,
                              void* d_out, int out_size, void* d_ws, size_t ws_size,
                              hipStream_t stream) {
  const float* proj = (const float*)d_in[0];
  const int*   tgt  = (const int*)d_in[1];
  float* out = (float*)d_out;

  char* ws = (char*)d_ws;
  unsigned short* p16  = (unsigned short*)ws;                        // 8 MB
  float* dpart = (float*)(ws + (size_t)8 * 1024 * 1024);             // 1 MB (32 x 8192)
  float* spart = (float*)(ws + (size_t)9 * 1024 * 1024);             // 1 MB

  normalize_rows<<<N_ROWS / 4, 256, 0, stream>>>(proj, p16);
  supcon_tile<<<NTRI, 1024, 0, stream>>>(p16, tgt, dpart, spart);
  combine_loss<<<N_ROWS / 64, 256, 0, stream>>>(dpart, spart, tgt, out);
}

// Round 16
// 96.654 us; speedup vs baseline: 1.2212x; 1.0225x over previous
//
#include <hip/hip_runtime.h>
#include <hip/hip_bf16.h>
#include <math.h>

// ---------------- problem constants ----------------
#define N_ROWS 8192
#define DIM    512
#define NCLS   64
#define BM     256   // tile rows/cols (16 waves of 64x64)
#define BK     64    // K step
#define NKT    (DIM / BK)                    // 8 K-tiles
#define NTILE  (N_ROWS / BM)                 // 32 tile-blocks per side
#define NTRI   (NTILE * (NTILE + 1) / 2)     // 528 upper-tri tiles = 8 * 66
#define NSLOT  NTILE                         // 32 partial slots
#define M_CONST 14.285714285714286f          // 1/T : the fixed max-shift (diagonal)
#define L2E     1.4426950408889634f          // log2(e)
#define M2_CONST 20.60992915555662f          // log2(e)/T (shift in exp2 units)
#define SCALE2  4.539815541256959f           // sqrt(log2(e)/T): MFMA outputs log2e*sim

using bf16x8 = __attribute__((ext_vector_type(8))) short;
using f32x4  = __attribute__((ext_vector_type(4))) float;

static __device__ inline unsigned short f2bf(float x) {
  unsigned u = __float_as_uint(x);
  unsigned r = u + 0x7FFFu + ((u >> 16) & 1u);   // RNE
  return (unsigned short)(r >> 16);
}

// ---- kernel 1: L2-normalize rows, scale by sqrt(log2e/T), cast bf16 -----------
__global__ __launch_bounds__(256) void normalize_rows(const float* __restrict__ proj,
                                                      unsigned short* __restrict__ outb) {
  const int row  = blockIdx.x * 4 + (threadIdx.x >> 6);
  const int lane = threadIdx.x & 63;
  const float4* src = (const float4*)(proj + (size_t)row * DIM);
  float4 a = src[lane * 2];
  float4 b = src[lane * 2 + 1];
  float ss = a.x*a.x + a.y*a.y + a.z*a.z + a.w*a.w
           + b.x*b.x + b.y*b.y + b.z*b.z + b.w*b.w;
#pragma unroll
  for (int off = 1; off < 64; off <<= 1) ss += __shfl_xor(ss, off);
  const float scale = SCALE2 / fmaxf(sqrtf(ss), 1e-12f);
  float v[8] = {a.x, a.y, a.z, a.w, b.x, b.y, b.z, b.w};
  unsigned short h[8];
#pragma unroll
  for (int i = 0; i < 8; ++i) h[i] = f2bf(v[i] * scale);
  uint4 packed;
  packed.x = (unsigned)h[0] | ((unsigned)h[1] << 16);
  packed.y = (unsigned)h[2] | ((unsigned)h[3] << 16);
  packed.z = (unsigned)h[4] | ((unsigned)h[5] << 16);
  packed.w = (unsigned)h[6] | ((unsigned)h[7] << 16);
  *(uint4*)(outb + (size_t)row * DIM + lane * 8) = packed;
}

// ---- kernel 2: 256^2 tile, 16 waves of 64x64, minimal-address-arith edition ----
// R14/R15 geometry, but LDS-read addressing collapsed: the swizzle key
// (Ra&7) == (llo&7) is UNIFORM across mi/ni (wm*64, mi*16 are 0 mod 8), so
// all fragment reads are ONE per-(ks) base VGPR + compile-time immediate
// (mi*2048B / ni*2048B / cur*32768B, all < 64KB ds_read offset range).
// This cuts arch-register demand under the 64-arch half of the 128 budget
// forced by 16-wave blocks (arch 64 + acc 64) -> no spill (R14/R15 spilled
// ~22 regs/thread, WRITE_SIZE 48.5MB). amdgpu_waves_per_eu(4,4) pins the
// 4-wave/SIMD budget. Schedule: R9's counted-vmcnt body (vmcnt(4), raw
// barrier pair, never drain mid-loop).
__attribute__((amdgpu_waves_per_eu(4, 4)))
__global__ __launch_bounds__(1024) void supcon_tile(const unsigned short* __restrict__ p16,
                                                    const int* __restrict__ tgt,
                                                    float* __restrict__ dpart,
                                                    float* __restrict__ spart) {
  // XCD-chunked bijective remap (528 % 8 == 0), then triangle decode
  const int logical = ((int)blockIdx.x & 7) * (NTRI / 8) + ((int)blockIdx.x >> 3);
  int rem = logical, br = 0;
  while (rem >= NTILE - br) { rem -= NTILE - br; ++br; }
  const int bc = br + rem;

  __shared__ short As[2][BM * BK];   // 2 x 32 KB
  __shared__ short Bs[2][BM * BK];   // 2 x 32 KB
  __shared__ int   tgr[BM], tgc[BM];
  __shared__ float redE[4][BM], redS[4][BM];     // row partials per wn (4 col-strips)
  __shared__ float redEc[4][BM], redSc[4][BM];   // col partials per wm (4 row-bands)

  const int tid  = threadIdx.x;
  const int lane = tid & 63;
  const int wid  = tid >> 6;          // 0..15
  const int wm = wid >> 2, wn = wid & 3;          // 4x4 grid of 64x64 wave-tiles
  const int lhi = lane >> 4, llo = lane & 15;
  const int swz = llo & 7;

  // fragment-read bases (element index); mi/ni add compile-time 1024-elt steps
  const int aoff = (wm * 64 + llo) * BK;
  const int boff = (wn * 64 + llo) * BK;
  const int kc0  = ((lhi) ^ swz) * 8;        // ks = 0 column byte-group
  const int kc1  = ((4 + lhi) ^ swz) * 8;    // ks = 1

  const size_t rowA0 = (size_t)br * BM;
  const size_t rowB0 = (size_t)bc * BM;

  // staging: 2048 granules (16B) per array; thread covers g = tid, tid+1024.
  // LDS dest linear in g; source granule pre-swizzled (key r&7 == (tid>>3)&7,
  // constant across j since j adds 128 rows). 4 loads/thread.
#define STAGE(BUF, KT) do {                                                         \
  _Pragma("unroll")                                                                 \
  for (int j = 0; j < 2; ++j) {                                                     \
    const int g  = tid + j * 1024;                                                  \
    const int r  = g >> 3, gp = g & 7;                                              \
    const int gl = gp ^ (r & 7);                                                    \
    const unsigned short* sA = p16 + (rowA0 + r) * DIM + (KT) * BK + gl * 8;        \
    const unsigned short* sB = p16 + (rowB0 + r) * DIM + (KT) * BK + gl * 8;        \
    __builtin_amdgcn_global_load_lds((const __attribute__((address_space(1))) void*)sA, \
        (__attribute__((address_space(3))) void*)&As[BUF][g * 8], 16, 0, 0);        \
    __builtin_amdgcn_global_load_lds((const __attribute__((address_space(1))) void*)sB, \
        (__attribute__((address_space(3))) void*)&Bs[BUF][g * 8], 16, 0, 0);        \
  }                                                                                 \
} while (0)

  STAGE(0, 0);
  if (tid < BM)            tgr[tid] = tgt[br * BM + tid];          // GUARDED
  else if (tid < 2 * BM)   tgc[tid - BM] = tgt[bc * BM + (tid - BM)];

  f32x4 zero = {0.f, 0.f, 0.f, 0.f};
  f32x4 acc[4][4];
#pragma unroll
  for (int i = 0; i < 4; ++i)
#pragma unroll
    for (int j = 0; j < 4; ++j) acc[i][j] = zero;

  __syncthreads();   // prologue drain; buf0 + targets ready

#pragma unroll
  for (int kt = 0; kt < NKT; ++kt) {
    const int cur = kt & 1, nxt = cur ^ 1;

    if (kt > 0) {
      __builtin_amdgcn_s_barrier();     // buf[nxt] reads (tile kt-1) done
      __builtin_amdgcn_sched_barrier(0);
    }
    if (kt + 1 < NKT) {
      STAGE(nxt, kt + 1);                              // 4 loads stay in flight
      asm volatile("s_waitcnt vmcnt(4)" ::: "memory"); // waits ONLY tile kt's
    } else {
      asm volatile("s_waitcnt vmcnt(0)" ::: "memory");
    }
    __builtin_amdgcn_sched_barrier(0);
    __builtin_amdgcn_s_barrier();                      // loads(kt) landed
    __builtin_amdgcn_sched_barrier(0);

    // single per-(cur,ks) base + immediate-offset fragment reads
    const short* As_c = &As[cur][aoff];
    const short* Bs_c = &Bs[cur][boff];
#pragma unroll
    for (int ks = 0; ks < 2; ++ks) {
      const int kc = ks ? kc1 : kc0;
      bf16x8 af[4], bfr[4];
#pragma unroll
      for (int mi = 0; mi < 4; ++mi)
        af[mi] = *(const bf16x8*)(As_c + kc + mi * (16 * BK));
#pragma unroll
      for (int ni = 0; ni < 4; ++ni)
        bfr[ni] = *(const bf16x8*)(Bs_c + kc + ni * (16 * BK));
#pragma unroll
      for (int mi = 0; mi < 4; ++mi)
#pragma unroll
        for (int ni = 0; ni < 4; ++ni)
          acc[mi][ni] = __builtin_amdgcn_mfma_f32_16x16x32_bf16(af[mi], bfr[ni], acc[mi][ni], 0, 0, 0);
    }
  }
#undef STAGE

  // ---- epilogue (exp2 units): acc = log2e*sim; e = exp2(acc - M2) ------------
  const bool diag = (br == bc);
  int tc[4];
#pragma unroll
  for (int ni = 0; ni < 4; ++ni) tc[ni] = tgc[wn * 64 + ni * 16 + llo];
  float ecol[4] = {0.f, 0.f, 0.f, 0.f};
  float scol[4] = {0.f, 0.f, 0.f, 0.f};

#pragma unroll
  for (int mi = 0; mi < 4; ++mi) {
#pragma unroll
    for (int rg = 0; rg < 4; ++rg) {
      const int rin  = wm * 64 + mi * 16 + lhi * 4 + rg;   // row within tile
      const int trow = tgr[rin];
      float esum = 0.f, ssum = 0.f;
#pragma unroll
      for (int ni = 0; ni < 4; ++ni) {
        const int cin = wn * 64 + ni * 16 + llo;           // col within tile
        const float x = acc[mi][ni][rg];                   // log2e * sim
        const bool self = diag && (rin == cin);
        const float e = self ? 0.f : __builtin_amdgcn_exp2f(x - M2_CONST);
        const bool pos = (!self) && (trow == tc[ni]);
        const float sv = pos ? x : 0.f;
        esum += e;  ssum += sv;
        ecol[ni] += e;  scol[ni] += sv;
      }
#pragma unroll
      for (int off = 1; off < 16; off <<= 1) {
        esum += __shfl_xor(esum, off);
        ssum += __shfl_xor(ssum, off);
      }
      if (llo == 0) { redE[wn][rin] = esum; redS[wn][rin] = ssum; }
    }
  }
  if (!diag) {  // transpose contribution: column sums -> rows of block bc
#pragma unroll
    for (int ni = 0; ni < 4; ++ni) {
      float ec = ecol[ni], sc = scol[ni];
      ec += __shfl_xor(ec, 16); ec += __shfl_xor(ec, 32);
      sc += __shfl_xor(sc, 16); sc += __shfl_xor(sc, 32);
      if (lhi == 0) {
        redEc[wm][wn * 64 + ni * 16 + llo] = ec;
        redSc[wm][wn * 64 + ni * 16 + llo] = sc;
      }
    }
  }
  __syncthreads();

  // cross-wave reduce; each [slot][row] cell written by exactly one block:
  // row-path of (br,bc) under slot bc; col-path under slot br (br!=bc).
  if (tid < BM) {
    const float e = redE[0][tid] + redE[1][tid] + redE[2][tid] + redE[3][tid];
    const float s = redS[0][tid] + redS[1][tid] + redS[2][tid] + redS[3][tid];
    dpart[(size_t)bc * N_ROWS + rowA0 + tid] = e;
    spart[(size_t)bc * N_ROWS + rowA0 + tid] = s;
  } else if (tid < 2 * BM && !diag) {
    const int c = tid - BM;
    dpart[(size_t)br * N_ROWS + rowB0 + c] = redEc[0][c] + redEc[1][c] + redEc[2][c] + redEc[3][c];
    spart[(size_t)br * N_ROWS + rowB0 + c] = redSc[0][c] + redSc[1][c] + redSc[2][c] + redSc[3][c];
  }
}

// ---- kernel 3: combine partials -> per-sample loss (hist inlined) -------------
__global__ __launch_bounds__(256) void combine_loss(const float* __restrict__ dpart,
                                                    const float* __restrict__ spart,
                                                    const int* __restrict__ tgt,
                                                    float* __restrict__ out) {
  __shared__ float dsh[4][64], ssh[4][64];
  __shared__ int   hloc[NCLS];
  const int tid  = threadIdx.x;
  const int lane = tid & 63;
  const int g    = tid >> 6;
  const int r    = blockIdx.x * 64 + lane;

  if (tid < NCLS) hloc[tid] = 0;
  __syncthreads();
  for (int i = tid; i < N_ROWS; i += 256) atomicAdd(&hloc[tgt[i]], 1);

  float d = 0.f, s = 0.f;
  for (int k = g * (NSLOT / 4); k < (g + 1) * (NSLOT / 4); ++k) {
    d += dpart[(size_t)k * N_ROWS + r];
    s += spart[(size_t)k * N_ROWS + r];
  }
  dsh[g][lane] = d; ssh[g][lane] = s;
  __syncthreads();
  if (g == 0) {
    d = dsh[0][lane] + dsh[1][lane] + dsh[2][lane] + dsh[3][lane];
    s = ssh[0][lane] + ssh[1][lane] + ssh[2][lane] + ssh[3][lane];
    const int cnt = hloc[tgt[r]] - 1;
    // s is in log2e*sim units -> divide back by L2E
    out[r] = (cnt > 0) ? (s / (L2E * (float)cnt) - M_CONST - logf(d + 1e-8f)) : 0.f;
  }
}

// ---------------- launcher ----------------
extern "C" void kernel_launch(void* const* d_in, const int* in_sizes, int n_in,
                              void* d_out, int out_size, void* d_ws, size_t ws_size,
                              hipStream_t stream) {
  const float* proj = (const float*)d_in[0];
  const int*   tgt  = (const int*)d_in[1];
  float* out = (float*)d_out;

  char* ws = (char*)d_ws;
  unsigned short* p16  = (unsigned short*)ws;                        // 8 MB
  float* dpart = (float*)(ws + (size_t)8 * 1024 * 1024);             // 1 MB (32 x 8192)
  float* spart = (float*)(ws + (size_t)9 * 1024 * 1024);             // 1 MB

  normalize_rows<<<N_ROWS / 4, 256, 0, stream>>>(proj, p16);
  supcon_tile<<<NTRI, 1024, 0, stream>>>(p16, tgt, dpart, spart);
  combine_loss<<<N_ROWS / 64, 256, 0, stream>>>(dpart, spart, tgt, out);
}